// Round 7
// baseline (214.344 us; speedup 1.0000x reference)
//
#include <hip/hip_runtime.h>
#include <hip/hip_fp16.h>
#include <stdint.h>

#define NB  32
#define NLQ 128
#define NLK 4096
#define NDK 256
#define NDV 256
#define KT  32
#define SPLITS 8

typedef _Float16 f16;
typedef _Float16 f16x4 __attribute__((ext_vector_type(4)));
typedef _Float16 f16x8 __attribute__((ext_vector_type(8)));
typedef float    f32x4 __attribute__((ext_vector_type(4)));

// ---------------- Kernel 1: per (key-split s, batch b) flash partials -------
// 8 waves x 16 queries = 128 queries per block.
// NO LDS staging, NO barriers in the main loop (r6 post-mortem: the per-tile
// K-prefetch barrier convoy was the stall; r0 proved this direct-from-global
// fragment pattern streams at ~2.9 TB/s). K and V PV/QK fragments are read
// f32 direct from global and converted to f16 in-reg; all 8 waves touch the
// same 32KB tiles -> HBM once, rest L1/L2. Masks preloaded to LDS once.
__global__ __launch_bounds__(512) void fvta_part1(
    const float* __restrict__ q_, const float* __restrict__ k_,
    const float* __restrict__ v_, const int* __restrict__ mask_,
    f16* __restrict__ accw, float* __restrict__ mlw)
{
    __shared__ int MK[NLK / SPLITS];

    const int tid = threadIdx.x, w = tid >> 6, lane = tid & 63;
    const int l15 = lane & 15, lhi = lane >> 4;
    const int s = blockIdx.x, b = blockIdx.y, S = gridDim.x;
    const int slice = NLK / S, nt = slice / KT, kbase = s * slice;
    const float NEG = -__builtin_inff();

    const float* kb = k_ + ((size_t)b * NLK + kbase) * NDK;
    const float* vb = v_ + ((size_t)b * NLK + kbase) * NDV;
    const int*   mb = mask_ + b * NLK + kbase;

    // ---- masks for the whole slice -> LDS (single barrier, before the loop)
    for (int i = tid; i < slice; i += 512) MK[i] = mb[i];

    // ---- Q fragments: lane holds Q[w*16+l15][kd*32 + lhi*8 + 0..8)
    f16x8 qf[8];
    {
        const float* qrow = q_ + ((size_t)b * NLQ + w * 16 + l15) * NDK + lhi * 8;
        #pragma unroll
        for (int kd = 0; kd < 8; ++kd) {
            f32x4 x = *(const f32x4*)(qrow + kd * 32);
            f32x4 y = *(const f32x4*)(qrow + kd * 32 + 4);
            f16x8 f;
            f[0]=(f16)x[0]; f[1]=(f16)x[1]; f[2]=(f16)x[2]; f[3]=(f16)x[3];
            f[4]=(f16)y[0]; f[5]=(f16)y[1]; f[6]=(f16)y[2]; f[7]=(f16)y[3];
            qf[kd] = f;
        }
    }

    f32x4 accu[16];
    #pragma unroll
    for (int i = 0; i < 16; ++i) accu[i] = (f32x4){0.f, 0.f, 0.f, 0.f};
    float m_run = NEG, l_run = 0.f;

    __syncthreads();   // MK ready; no further barriers

    for (int t = 0; t < nt; ++t) {
        const int k0 = t * KT;

        // ---- QK^T, both 16-key halves: A = K rows, f32 direct from global
        f32x4 s4a = (f32x4){0.f,0.f,0.f,0.f}, s4b = s4a;
        {
            const float* ka_row = kb + (size_t)(k0 + l15) * NDK + lhi * 8;
            const float* kb_row = ka_row + 16 * NDK;
            #pragma unroll
            for (int kd = 0; kd < 8; ++kd) {
                f32x4 xa = *(const f32x4*)(ka_row + kd * 32);
                f32x4 ya = *(const f32x4*)(ka_row + kd * 32 + 4);
                f32x4 xb = *(const f32x4*)(kb_row + kd * 32);
                f32x4 yb = *(const f32x4*)(kb_row + kd * 32 + 4);
                f16x8 kfa, kfb;
                kfa[0]=(f16)xa[0]; kfa[1]=(f16)xa[1]; kfa[2]=(f16)xa[2]; kfa[3]=(f16)xa[3];
                kfa[4]=(f16)ya[0]; kfa[5]=(f16)ya[1]; kfa[6]=(f16)ya[2]; kfa[7]=(f16)ya[3];
                kfb[0]=(f16)xb[0]; kfb[1]=(f16)xb[1]; kfb[2]=(f16)xb[2]; kfb[3]=(f16)xb[3];
                kfb[4]=(f16)yb[0]; kfb[5]=(f16)yb[1]; kfb[6]=(f16)yb[2]; kfb[7]=(f16)yb[3];
                s4a = __builtin_amdgcn_mfma_f32_16x16x32_f16(kfa, qf[kd], s4a, 0, 0, 0);
                s4b = __builtin_amdgcn_mfma_f32_16x16x32_f16(kfb, qf[kd], s4b, 0, 0, 0);
            }
        }
        // s4a[j] = S[key=k0+lhi*4+j][q=l15], s4b[j] = S[key=k0+16+lhi*4+j][q=l15]

        // ---- mask -> -inf (from LDS), online softmax over 32 keys
        const int4 m4a = *(const int4*)(MK + k0 + lhi * 4);
        const int4 m4b = *(const int4*)(MK + k0 + 16 + lhi * 4);
        float sa[4], sb[4];
        sa[0] = m4a.x ? NEG : s4a[0]; sa[1] = m4a.y ? NEG : s4a[1];
        sa[2] = m4a.z ? NEG : s4a[2]; sa[3] = m4a.w ? NEG : s4a[3];
        sb[0] = m4b.x ? NEG : s4b[0]; sb[1] = m4b.y ? NEG : s4b[1];
        sb[2] = m4b.z ? NEG : s4b[2]; sb[3] = m4b.w ? NEG : s4b[3];

        float tmax = fmaxf(fmaxf(fmaxf(sa[0], sa[1]), fmaxf(sa[2], sa[3])),
                           fmaxf(fmaxf(sb[0], sb[1]), fmaxf(sb[2], sb[3])));
        tmax = fmaxf(tmax, __shfl_xor(tmax, 16, 64));
        tmax = fmaxf(tmax, __shfl_xor(tmax, 32, 64));
        const float mnew = fmaxf(m_run, tmax);
        const bool  dead = (mnew == NEG);
        const float scale = dead ? 1.f : __expf(m_run - mnew);
        float pa4[4], pb4[4];
        #pragma unroll
        for (int j = 0; j < 4; ++j) {
            pa4[j] = dead ? 0.f : __expf(sa[j] - mnew);
            pb4[j] = dead ? 0.f : __expf(sb[j] - mnew);
        }
        float ps = (pa4[0] + pa4[1]) + (pa4[2] + pa4[3])
                 + (pb4[0] + pb4[1]) + (pb4[2] + pb4[3]);
        ps += __shfl_xor(ps, 16, 64);
        ps += __shfl_xor(ps, 32, 64);
        l_run = l_run * scale + ps;
        m_run = mnew;

        f16x4 pa, pb;
        pa[0]=(f16)pa4[0]; pa[1]=(f16)pa4[1]; pa[2]=(f16)pa4[2]; pa[3]=(f16)pa4[3];
        pb[0]=(f16)pb4[0]; pb[1]=(f16)pb4[1]; pb[2]=(f16)pb4[2]; pb[3]=(f16)pb4[3];

        if (!__all(scale == 1.f)) {
            float scj[4];
            #pragma unroll
            for (int j = 0; j < 4; ++j) scj[j] = __shfl(scale, lhi * 4 + j, 64);
            #pragma unroll
            for (int d = 0; d < 16; ++d) {
                accu[d][0] *= scj[0]; accu[d][1] *= scj[1];
                accu[d][2] *= scj[2]; accu[d][3] *= scj[3];
            }
        }

        // ---- PV: B frag = V[row=h*16+lhi*4+j][dv=d*16+l15], f32 direct from
        // global (r0-verified). 4-d groups: 16 independent loads, cvt, 4 MFMA.
        {
            const float* vr = vb + (size_t)(k0 + lhi * 4) * NDV + l15;
            #pragma unroll
            for (int h = 0; h < 2; ++h) {
                const f16x4 pfrag = h ? pb : pa;
                const float* vh = vr + (size_t)h * 16 * NDV;
                #pragma unroll
                for (int dg = 0; dg < 4; ++dg) {
                    float tv[4][4];
                    #pragma unroll
                    for (int dd = 0; dd < 4; ++dd) {
                        const float* vc = vh + (dg * 4 + dd) * 16;
                        tv[dd][0] = vc[0];
                        tv[dd][1] = vc[1 * NDV];
                        tv[dd][2] = vc[2 * NDV];
                        tv[dd][3] = vc[3 * NDV];
                    }
                    #pragma unroll
                    for (int dd = 0; dd < 4; ++dd) {
                        f16x4 vf;
                        vf[0]=(f16)tv[dd][0]; vf[1]=(f16)tv[dd][1];
                        vf[2]=(f16)tv[dd][2]; vf[3]=(f16)tv[dd][3];
                        accu[dg * 4 + dd] = __builtin_amdgcn_mfma_f32_16x16x16f16(
                            pfrag, vf, accu[dg * 4 + dd], 0, 0, 0);
                    }
                }
            }
        }
    }

    // ---- write partials {acc (f16), m, l (f32)} to workspace
    const size_t base = (size_t)(b * S + s) * NLQ + w * 16;
    #pragma unroll
    for (int j = 0; j < 4; ++j) {
        f16* dst = accw + (base + lhi * 4 + j) * NDV + l15;
        #pragma unroll
        for (int d = 0; d < 16; ++d) dst[d * 16] = (f16)accu[d][j];
    }
    if (lane < 16) {
        mlw[(base + lane) * 2]     = m_run;
        mlw[(base + lane) * 2 + 1] = l_run;
    }
}

// ---------------- Kernel 2: merge key-splits, q-length mask, mean ----------
// 8 queries per block (512 blocks) — halves the serial per-thread loop.
__global__ __launch_bounds__(256) void fvta_merge(
    const f16* __restrict__ accw, const float* __restrict__ mlw,
    const int* __restrict__ qlen_, float* __restrict__ out_, int S)
{
    __shared__ float fac[8][SPLITS + 1];
    const int qc = blockIdx.x, b = blockIdx.y, tid = threadIdx.x;
    const int len = qlen_[b];
    const float NEG = -__builtin_inff();

    if (tid < 8) {
        const int q = qc * 8 + tid;
        if (q < len) {
            float gm = NEG;
            for (int ss = 0; ss < S; ++ss)
                gm = fmaxf(gm, mlw[((size_t)(b * S + ss) * NLQ + q) * 2]);
            float L = 0.f;
            for (int ss = 0; ss < S; ++ss) {
                const float m = mlw[((size_t)(b * S + ss) * NLQ + q) * 2];
                const float l = mlw[((size_t)(b * S + ss) * NLQ + q) * 2 + 1];
                if (m != NEG) L += l * __expf(m - gm);
            }
            for (int ss = 0; ss < S; ++ss) {
                const float m = mlw[((size_t)(b * S + ss) * NLQ + q) * 2];
                fac[tid][ss] = (gm != NEG && L > 0.f && m != NEG)
                             ? __expf(m - gm) / L : 0.f;
            }
        } else {
            for (int ss = 0; ss < S; ++ss) fac[tid][ss] = 0.f;
        }
    }
    __syncthreads();

    float sum = 0.f;
    for (int qq = 0; qq < 8; ++qq) {
        const int q = qc * 8 + qq;
        for (int ss = 0; ss < S; ++ss) {
            const float f = fac[qq][ss];
            if (f != 0.f)
                sum += (float)accw[((size_t)(b * S + ss) * NLQ + q) * NDV + tid] * f;
        }
    }
    atomicAdd(&out_[b * NDV + tid], sum * (1.f / NLQ));
}

extern "C" void kernel_launch(void* const* d_in, const int* in_sizes, int n_in,
                              void* d_out, int out_size, void* d_ws, size_t ws_size,
                              hipStream_t stream) {
    const float* q    = (const float*)d_in[0];
    const int*   qlen = (const int*)d_in[1];
    const float* k    = (const float*)d_in[2];
    const float* v    = (const float*)d_in[3];
    const int*   mask = (const int*)d_in[4];
    float* out = (float*)d_out;

    const int S = SPLITS;   // 16.8 MB + 0.26 MB workspace (ws has held >33 MB)
    f16*   accw = (f16*)d_ws;
    float* mlw  = (float*)((char*)d_ws + (size_t)NB * S * NLQ * NDV * 2);

    hipMemsetAsync(out, 0, (size_t)out_size * sizeof(float), stream);
    dim3 g1(S, NB);
    fvta_part1<<<g1, 512, 0, stream>>>(q, k, v, mask, accw, mlw);
    dim3 g2(NLQ / 8, NB);
    fvta_merge<<<g2, 256, 0, stream>>>(accw, mlw, qlen, out, S);
}

// Round 8
// 152.022 us; speedup vs baseline: 1.4100x; 1.4100x over previous
//
#include <hip/hip_runtime.h>
#include <hip/hip_fp16.h>
#include <stdint.h>

#define NB  32
#define NLQ 128
#define NLK 4096
#define NDK 256
#define NDV 256
#define KT  32
#define SPLITS 16
#define MINSPLITS 4

typedef _Float16 f16;
typedef _Float16 f16x4 __attribute__((ext_vector_type(4)));
typedef _Float16 f16x8 __attribute__((ext_vector_type(8)));
typedef float    f32x4 __attribute__((ext_vector_type(4)));

// ---------------- Kernel 1: per (key-split s, batch b) flash partials -------
// 8 waves x 16 queries = 128 queries per block. r6 structure (best: 124us):
//   K: reg-staged f32->f16 swizzled dbuf LDS (1-tile prefetch, 0 conflicts)
//   V: PV B-fragments f32 DIRECT from global (beat LDS-V by 15%, r6 vs r5)
//   masks: slice preloaded to LDS once.
// r7 lesson: do NOT read K direct per-wave (shared-tile cache chain, -80%).
// S=16 -> 512 blocks: offers the scheduler 2 blocks/CU at 104 VGPR / 34KB LDS
// (r4/r5 A/B: 64-VGPR paired, 128 didn't; 104 untested until now).
__global__ __launch_bounds__(512) void fvta_part1(
    const float* __restrict__ q_, const float* __restrict__ k_,
    const float* __restrict__ v_, const int* __restrict__ mask_,
    f16* __restrict__ accw, float* __restrict__ mlw)
{
    __shared__ __align__(16) f16 KA[2][KT * NDK];
    __shared__ int MK[NLK / MINSPLITS];

    const int tid = threadIdx.x, w = tid >> 6, lane = tid & 63;
    const int l15 = lane & 15, lhi = lane >> 4;
    const int s = blockIdx.x, b = blockIdx.y, S = gridDim.x;
    const int slice = NLK / S, nt = slice / KT, kbase = s * slice;
    const float NEG = -__builtin_inff();

    const float* kb = k_ + ((size_t)b * NLK + kbase) * NDK;
    const float* vb = v_ + ((size_t)b * NLK + kbase) * NDV;
    const int*   mb = mask_ + b * NLK + kbase;

    // ---- masks for the whole slice -> LDS
    for (int i = tid; i < slice; i += 512) MK[i] = mb[i];

    // ---- Q fragments: lane holds Q[w*16+l15][kd*32 + lhi*8 + 0..8)
    f16x8 qf[8];
    {
        const float* qrow = q_ + ((size_t)b * NLQ + w * 16 + l15) * NDK + lhi * 8;
        #pragma unroll
        for (int kd = 0; kd < 8; ++kd) {
            f32x4 x = *(const f32x4*)(qrow + kd * 32);
            f32x4 y = *(const f32x4*)(qrow + kd * 32 + 4);
            f16x8 f;
            f[0]=(f16)x[0]; f[1]=(f16)x[1]; f[2]=(f16)x[2]; f[3]=(f16)x[3];
            f[4]=(f16)y[0]; f[5]=(f16)y[1]; f[6]=(f16)y[2]; f[7]=(f16)y[3];
            qf[kd] = f;
        }
    }

    f32x4 accu[16];
    #pragma unroll
    for (int i = 0; i < 16; ++i) accu[i] = (f32x4){0.f, 0.f, 0.f, 0.f};
    float m_run = NEG, l_run = 0.f;

    f32x4 ks[4];   // staged K f32 for next tile

    // thread's staging coords: kk = r*8 + w, d = lane*4 (K tile 32x256 f32)
    auto stage = [&](f16* KAb) {
        #pragma unroll
        for (int r = 0; r < 4; ++r) {
            const int kk = r * 8 + w;
            const int d  = lane * 4;
            const int e  = kk * NDK + (d ^ ((kk & 15) << 3));
            f32x4 x = ks[r];
            f16x4 hh; hh[0]=(f16)x[0]; hh[1]=(f16)x[1]; hh[2]=(f16)x[2]; hh[3]=(f16)x[3];
            *(f16x4*)(KAb + e) = hh;
        }
    };

    // prologue: load + stage K tile 0
    #pragma unroll
    for (int r = 0; r < 4; ++r)
        ks[r] = *(const f32x4*)(kb + (r * 512 + tid) * 4);
    stage(KA[0]);
    __syncthreads();

    const int swz = l15 << 3;   // K read swizzle: row&15 == l15 for both halves

    for (int t = 0; t < nt; ++t) {
        const int cur = t & 1;
        if (t + 1 < nt) {   // prefetch next K tile (in flight through compute)
            const float* ksrc = kb + (size_t)(t + 1) * KT * NDK;
            #pragma unroll
            for (int r = 0; r < 4; ++r)
                ks[r] = *(const f32x4*)(ksrc + (r * 512 + tid) * 4);
        }
        const int k0 = t * KT;

        // ---- QK^T, both 16-key halves (A = K rows from LDS, B = Q)
        f32x4 s4a = (f32x4){0.f,0.f,0.f,0.f}, s4b = s4a;
        {
            const f16* k0p = &KA[cur][(0 * 16 + l15) * NDK];
            const f16* k1p = &KA[cur][(1 * 16 + l15) * NDK];
            #pragma unroll
            for (int kd = 0; kd < 8; ++kd) {
                const int col = (kd * 32 + lhi * 8) ^ swz;
                f16x8 kfa = *(const f16x8*)(k0p + col);
                s4a = __builtin_amdgcn_mfma_f32_16x16x32_f16(kfa, qf[kd], s4a, 0, 0, 0);
                f16x8 kfb = *(const f16x8*)(k1p + col);
                s4b = __builtin_amdgcn_mfma_f32_16x16x32_f16(kfb, qf[kd], s4b, 0, 0, 0);
            }
        }
        // s4a[j] = S[key=k0+lhi*4+j][q=l15], s4b[j] = S[key=k0+16+lhi*4+j][q=l15]

        // ---- mask -> -inf (from LDS), online softmax over 32 keys
        const int4 m4a = *(const int4*)(MK + k0 + lhi * 4);
        const int4 m4b = *(const int4*)(MK + k0 + 16 + lhi * 4);
        float sa[4], sb[4];
        sa[0] = m4a.x ? NEG : s4a[0]; sa[1] = m4a.y ? NEG : s4a[1];
        sa[2] = m4a.z ? NEG : s4a[2]; sa[3] = m4a.w ? NEG : s4a[3];
        sb[0] = m4b.x ? NEG : s4b[0]; sb[1] = m4b.y ? NEG : s4b[1];
        sb[2] = m4b.z ? NEG : s4b[2]; sb[3] = m4b.w ? NEG : s4b[3];

        float tmax = fmaxf(fmaxf(fmaxf(sa[0], sa[1]), fmaxf(sa[2], sa[3])),
                           fmaxf(fmaxf(sb[0], sb[1]), fmaxf(sb[2], sb[3])));
        tmax = fmaxf(tmax, __shfl_xor(tmax, 16, 64));
        tmax = fmaxf(tmax, __shfl_xor(tmax, 32, 64));
        const float mnew = fmaxf(m_run, tmax);
        const bool  dead = (mnew == NEG);
        const float scale = dead ? 1.f : __expf(m_run - mnew);
        float pa4[4], pb4[4];
        #pragma unroll
        for (int j = 0; j < 4; ++j) {
            pa4[j] = dead ? 0.f : __expf(sa[j] - mnew);
            pb4[j] = dead ? 0.f : __expf(sb[j] - mnew);
        }
        float ps = (pa4[0] + pa4[1]) + (pa4[2] + pa4[3])
                 + (pb4[0] + pb4[1]) + (pb4[2] + pb4[3]);
        ps += __shfl_xor(ps, 16, 64);
        ps += __shfl_xor(ps, 32, 64);
        l_run = l_run * scale + ps;
        m_run = mnew;

        f16x4 pa, pb;
        pa[0]=(f16)pa4[0]; pa[1]=(f16)pa4[1]; pa[2]=(f16)pa4[2]; pa[3]=(f16)pa4[3];
        pb[0]=(f16)pb4[0]; pb[1]=(f16)pb4[1]; pb[2]=(f16)pb4[2]; pb[3]=(f16)pb4[3];

        if (!__all(scale == 1.f)) {
            float scj[4];
            #pragma unroll
            for (int j = 0; j < 4; ++j) scj[j] = __shfl(scale, lhi * 4 + j, 64);
            #pragma unroll
            for (int d = 0; d < 16; ++d) {
                accu[d][0] *= scj[0]; accu[d][1] *= scj[1];
                accu[d][2] *= scj[2]; accu[d][3] *= scj[3];
            }
        }

        // ---- PV: B frag = V[row=h*16+lhi*4+j][dv=d*16+l15], f32 direct from
        // global. 4-d groups: 16 independent loads, cvt, 4 MFMA.
        {
            const float* vr = vb + (size_t)(k0 + lhi * 4) * NDV + l15;
            #pragma unroll
            for (int h = 0; h < 2; ++h) {
                const f16x4 pfrag = h ? pb : pa;
                const float* vh = vr + (size_t)h * 16 * NDV;
                #pragma unroll
                for (int dg = 0; dg < 4; ++dg) {
                    float tv[4][4];
                    #pragma unroll
                    for (int dd = 0; dd < 4; ++dd) {
                        const float* vc = vh + (dg * 4 + dd) * 16;
                        tv[dd][0] = vc[0];
                        tv[dd][1] = vc[1 * NDV];
                        tv[dd][2] = vc[2 * NDV];
                        tv[dd][3] = vc[3 * NDV];
                    }
                    #pragma unroll
                    for (int dd = 0; dd < 4; ++dd) {
                        f16x4 vf;
                        vf[0]=(f16)tv[dd][0]; vf[1]=(f16)tv[dd][1];
                        vf[2]=(f16)tv[dd][2]; vf[3]=(f16)tv[dd][3];
                        accu[dg * 4 + dd] = __builtin_amdgcn_mfma_f32_16x16x16f16(
                            pfrag, vf, accu[dg * 4 + dd], 0, 0, 0);
                    }
                }
            }
        }

        if (t + 1 < nt) stage(KA[cur ^ 1]);
        __syncthreads();
    }

    // ---- write partials {acc (f16), m, l (f32)} to workspace
    const size_t base = (size_t)(b * S + s) * NLQ + w * 16;
    #pragma unroll
    for (int j = 0; j < 4; ++j) {
        f16* dst = accw + (base + lhi * 4 + j) * NDV + l15;
        #pragma unroll
        for (int d = 0; d < 16; ++d) dst[d * 16] = (f16)accu[d][j];
    }
    if (lane < 16) {
        mlw[(base + lane) * 2]     = m_run;
        mlw[(base + lane) * 2 + 1] = l_run;
    }
}

// ---------------- Kernel 2: merge key-splits, q-length mask, mean ----------
// 8 queries per block (512 blocks).
__global__ __launch_bounds__(256) void fvta_merge(
    const f16* __restrict__ accw, const float* __restrict__ mlw,
    const int* __restrict__ qlen_, float* __restrict__ out_, int S)
{
    __shared__ float fac[8][SPLITS + 1];
    const int qc = blockIdx.x, b = blockIdx.y, tid = threadIdx.x;
    const int len = qlen_[b];
    const float NEG = -__builtin_inff();

    if (tid < 8) {
        const int q = qc * 8 + tid;
        if (q < len) {
            float gm = NEG;
            for (int ss = 0; ss < S; ++ss)
                gm = fmaxf(gm, mlw[((size_t)(b * S + ss) * NLQ + q) * 2]);
            float L = 0.f;
            for (int ss = 0; ss < S; ++ss) {
                const float m = mlw[((size_t)(b * S + ss) * NLQ + q) * 2];
                const float l = mlw[((size_t)(b * S + ss) * NLQ + q) * 2 + 1];
                if (m != NEG) L += l * __expf(m - gm);
            }
            for (int ss = 0; ss < S; ++ss) {
                const float m = mlw[((size_t)(b * S + ss) * NLQ + q) * 2];
                fac[tid][ss] = (gm != NEG && L > 0.f && m != NEG)
                             ? __expf(m - gm) / L : 0.f;
            }
        } else {
            for (int ss = 0; ss < S; ++ss) fac[tid][ss] = 0.f;
        }
    }
    __syncthreads();

    float sum = 0.f;
    for (int qq = 0; qq < 8; ++qq) {
        const int q = qc * 8 + qq;
        for (int ss = 0; ss < S; ++ss) {
            const float f = fac[qq][ss];
            if (f != 0.f)
                sum += (float)accw[((size_t)(b * S + ss) * NLQ + q) * NDV + tid] * f;
        }
    }
    atomicAdd(&out_[b * NDV + tid], sum * (1.f / NLQ));
}

extern "C" void kernel_launch(void* const* d_in, const int* in_sizes, int n_in,
                              void* d_out, int out_size, void* d_ws, size_t ws_size,
                              hipStream_t stream) {
    const float* q    = (const float*)d_in[0];
    const int*   qlen = (const int*)d_in[1];
    const float* k    = (const float*)d_in[2];
    const float* v    = (const float*)d_in[3];
    const int*   mask = (const int*)d_in[4];
    float* out = (float*)d_out;

    int S = SPLITS;   // auto-halve if ws is small (S>=MINSPLITS for MK sizing)
    while (S > MINSPLITS &&
           ((size_t)NB * S * NLQ * NDV * 2 + (size_t)NB * S * NLQ * 8) > ws_size)
        S >>= 1;
    f16*   accw = (f16*)d_ws;
    float* mlw  = (float*)((char*)d_ws + (size_t)NB * S * NLQ * NDV * 2);

    hipMemsetAsync(out, 0, (size_t)out_size * sizeof(float), stream);
    dim3 g1(S, NB);
    fvta_part1<<<g1, 512, 0, stream>>>(q, k, v, mask, accw, mlw);
    dim3 g2(NLQ / 8, NB);
    fvta_merge<<<g2, 256, 0, stream>>>(accw, mlw, qlen, out, S);
}

// Round 9
// 123.345 us; speedup vs baseline: 1.7378x; 1.2325x over previous
//
#include <hip/hip_runtime.h>
#include <hip/hip_fp16.h>
#include <stdint.h>

#define NB  32
#define NLQ 128
#define NLK 4096
#define NDK 256
#define NDV 256
#define KT  16
#define SPLITS 8
#define MINSPLITS 4

typedef _Float16 f16;
typedef _Float16 f16x4 __attribute__((ext_vector_type(4)));
typedef _Float16 f16x8 __attribute__((ext_vector_type(8)));
typedef float    f32x4 __attribute__((ext_vector_type(4)));

// ---------------- Kernel 1: per (key-split s, batch b, q-half) partials -----
// 4 waves x 16 queries = 64 queries per block, 256 threads.
// r8 post-mortem: 8-wave blocks never pair above ~64 VGPR (all-or-nothing
// 2 wave-slots/SIMD). 4-wave blocks need only 1 slot/SIMD -> 3-4 blocks/CU
// co-resident at the same 104 VGPR. Compute identical to r6 (best kernel):
//   K: reg-staged f32->f16 swizzled dbuf LDS (KT=16 so ks[] stays 4 regs)
//   V: PV B-fragments f32 DIRECT from global (r6-proven; r7 proved K must
//      NOT be direct)   masks: slice preloaded to LDS once.
__global__ __launch_bounds__(256) void fvta_part1(
    const float* __restrict__ q_, const float* __restrict__ k_,
    const float* __restrict__ v_, const int* __restrict__ mask_,
    f16* __restrict__ accw, float* __restrict__ mlw)
{
    __shared__ __align__(16) f16 KA[2][KT * NDK];   // 2 x 8 KB
    __shared__ int MK[NLK / MINSPLITS];             // 4 KB

    const int tid = threadIdx.x, w = tid >> 6, lane = tid & 63;
    const int l15 = lane & 15, lhi = lane >> 4;
    const int s = blockIdx.x, b = blockIdx.y, qh = blockIdx.z, S = gridDim.x;
    const int slice = NLK / S, nt = slice / KT, kbase = s * slice;
    const float NEG = -__builtin_inff();

    const float* kb = k_ + ((size_t)b * NLK + kbase) * NDK;
    const float* vb = v_ + ((size_t)b * NLK + kbase) * NDV;
    const int*   mb = mask_ + b * NLK + kbase;

    // ---- masks for the whole slice -> LDS
    for (int i = tid; i < slice; i += 256) MK[i] = mb[i];

    // ---- Q fragments: lane holds Q[qh*64+w*16+l15][kd*32 + lhi*8 + 0..8)
    f16x8 qf[8];
    {
        const float* qrow = q_ + ((size_t)b * NLQ + qh * 64 + w * 16 + l15) * NDK + lhi * 8;
        #pragma unroll
        for (int kd = 0; kd < 8; ++kd) {
            f32x4 x = *(const f32x4*)(qrow + kd * 32);
            f32x4 y = *(const f32x4*)(qrow + kd * 32 + 4);
            f16x8 f;
            f[0]=(f16)x[0]; f[1]=(f16)x[1]; f[2]=(f16)x[2]; f[3]=(f16)x[3];
            f[4]=(f16)y[0]; f[5]=(f16)y[1]; f[6]=(f16)y[2]; f[7]=(f16)y[3];
            qf[kd] = f;
        }
    }

    f32x4 accu[16];
    #pragma unroll
    for (int i = 0; i < 16; ++i) accu[i] = (f32x4){0.f, 0.f, 0.f, 0.f};
    float m_run = NEG, l_run = 0.f;

    f32x4 ks[4];   // staged K f32 for next tile (16x256 f32 / 256 threads)

    // thread's staging coords: idx = r*256+tid -> kk = idx>>6, d = (idx&63)*4
    auto stage = [&](f16* KAb) {
        #pragma unroll
        for (int r = 0; r < 4; ++r) {
            const int idx = r * 256 + tid;
            const int kk  = idx >> 6;
            const int d   = (idx & 63) * 4;
            const int e   = kk * NDK + (d ^ (kk << 3));   // kk < 16
            f32x4 x = ks[r];
            f16x4 hh; hh[0]=(f16)x[0]; hh[1]=(f16)x[1]; hh[2]=(f16)x[2]; hh[3]=(f16)x[3];
            *(f16x4*)(KAb + e) = hh;
        }
    };

    // prologue: load + stage K tile 0
    #pragma unroll
    for (int r = 0; r < 4; ++r)
        ks[r] = *(const f32x4*)(kb + (r * 256 + tid) * 4);
    stage(KA[0]);
    __syncthreads();

    const int swz = l15 << 3;   // K read swizzle: row == l15

    for (int t = 0; t < nt; ++t) {
        const int cur = t & 1;
        if (t + 1 < nt) {   // prefetch next K tile (in flight through compute)
            const float* ksrc = kb + (size_t)(t + 1) * KT * NDK;
            #pragma unroll
            for (int r = 0; r < 4; ++r)
                ks[r] = *(const f32x4*)(ksrc + (r * 256 + tid) * 4);
        }
        const int k0 = t * KT;

        // ---- QK^T over 16 keys (A = K rows from LDS, B = Q)
        f32x4 s4 = (f32x4){0.f,0.f,0.f,0.f};
        {
            const f16* kp = &KA[cur][l15 * NDK];
            #pragma unroll
            for (int kd = 0; kd < 8; ++kd) {
                const int col = (kd * 32 + lhi * 8) ^ swz;
                f16x8 kf = *(const f16x8*)(kp + col);
                s4 = __builtin_amdgcn_mfma_f32_16x16x32_f16(kf, qf[kd], s4, 0, 0, 0);
            }
        }
        // s4[j] = S[key=k0+lhi*4+j][q=l15]

        // ---- mask -> -inf (from LDS), online softmax over 16 keys
        const int4 m4 = *(const int4*)(MK + k0 + lhi * 4);
        float sa[4];
        sa[0] = m4.x ? NEG : s4[0]; sa[1] = m4.y ? NEG : s4[1];
        sa[2] = m4.z ? NEG : s4[2]; sa[3] = m4.w ? NEG : s4[3];

        float tmax = fmaxf(fmaxf(sa[0], sa[1]), fmaxf(sa[2], sa[3]));
        tmax = fmaxf(tmax, __shfl_xor(tmax, 16, 64));
        tmax = fmaxf(tmax, __shfl_xor(tmax, 32, 64));
        const float mnew = fmaxf(m_run, tmax);
        const bool  dead = (mnew == NEG);
        const float scale = dead ? 1.f : __expf(m_run - mnew);
        float p4[4];
        #pragma unroll
        for (int j = 0; j < 4; ++j) p4[j] = dead ? 0.f : __expf(sa[j] - mnew);
        float ps = (p4[0] + p4[1]) + (p4[2] + p4[3]);
        ps += __shfl_xor(ps, 16, 64);
        ps += __shfl_xor(ps, 32, 64);
        l_run = l_run * scale + ps;
        m_run = mnew;

        f16x4 pa;
        pa[0]=(f16)p4[0]; pa[1]=(f16)p4[1]; pa[2]=(f16)p4[2]; pa[3]=(f16)p4[3];

        if (!__all(scale == 1.f)) {
            float scj[4];
            #pragma unroll
            for (int j = 0; j < 4; ++j) scj[j] = __shfl(scale, lhi * 4 + j, 64);
            #pragma unroll
            for (int d = 0; d < 16; ++d) {
                accu[d][0] *= scj[0]; accu[d][1] *= scj[1];
                accu[d][2] *= scj[2]; accu[d][3] *= scj[3];
            }
        }

        // ---- PV: B frag = V[row=k0+lhi*4+j][dv=d*16+l15], f32 direct from
        // global. 4-d groups: 16 independent loads, cvt, 4 MFMA.
        {
            const float* vr = vb + (size_t)(k0 + lhi * 4) * NDV + l15;
            #pragma unroll
            for (int dg = 0; dg < 4; ++dg) {
                float tv[4][4];
                #pragma unroll
                for (int dd = 0; dd < 4; ++dd) {
                    const float* vc = vr + (dg * 4 + dd) * 16;
                    tv[dd][0] = vc[0];
                    tv[dd][1] = vc[1 * NDV];
                    tv[dd][2] = vc[2 * NDV];
                    tv[dd][3] = vc[3 * NDV];
                }
                #pragma unroll
                for (int dd = 0; dd < 4; ++dd) {
                    f16x4 vf;
                    vf[0]=(f16)tv[dd][0]; vf[1]=(f16)tv[dd][1];
                    vf[2]=(f16)tv[dd][2]; vf[3]=(f16)tv[dd][3];
                    accu[dg * 4 + dd] = __builtin_amdgcn_mfma_f32_16x16x16f16(
                        pa, vf, accu[dg * 4 + dd], 0, 0, 0);
                }
            }
        }

        if (t + 1 < nt) stage(KA[cur ^ 1]);
        __syncthreads();
    }

    // ---- write partials {acc (f16), m, l (f32)} to workspace
    const size_t base = (size_t)(b * S + s) * NLQ + qh * 64 + w * 16;
    #pragma unroll
    for (int j = 0; j < 4; ++j) {
        f16* dst = accw + (base + lhi * 4 + j) * NDV + l15;
        #pragma unroll
        for (int d = 0; d < 16; ++d) dst[d * 16] = (f16)accu[d][j];
    }
    if (lane < 16) {
        mlw[(base + lane) * 2]     = m_run;
        mlw[(base + lane) * 2 + 1] = l_run;
    }
}

// ---------------- Kernel 2: merge key-splits, q-length mask, mean ----------
// 8 queries per block (512 blocks).
__global__ __launch_bounds__(256) void fvta_merge(
    const f16* __restrict__ accw, const float* __restrict__ mlw,
    const int* __restrict__ qlen_, float* __restrict__ out_, int S)
{
    __shared__ float fac[8][SPLITS + 1];
    const int qc = blockIdx.x, b = blockIdx.y, tid = threadIdx.x;
    const int len = qlen_[b];
    const float NEG = -__builtin_inff();

    if (tid < 8) {
        const int q = qc * 8 + tid;
        if (q < len) {
            float gm = NEG;
            for (int ss = 0; ss < S; ++ss)
                gm = fmaxf(gm, mlw[((size_t)(b * S + ss) * NLQ + q) * 2]);
            float L = 0.f;
            for (int ss = 0; ss < S; ++ss) {
                const float m = mlw[((size_t)(b * S + ss) * NLQ + q) * 2];
                const float l = mlw[((size_t)(b * S + ss) * NLQ + q) * 2 + 1];
                if (m != NEG) L += l * __expf(m - gm);
            }
            for (int ss = 0; ss < S; ++ss) {
                const float m = mlw[((size_t)(b * S + ss) * NLQ + q) * 2];
                fac[tid][ss] = (gm != NEG && L > 0.f && m != NEG)
                             ? __expf(m - gm) / L : 0.f;
            }
        } else {
            for (int ss = 0; ss < S; ++ss) fac[tid][ss] = 0.f;
        }
    }
    __syncthreads();

    float sum = 0.f;
    for (int qq = 0; qq < 8; ++qq) {
        const int q = qc * 8 + qq;
        for (int ss = 0; ss < S; ++ss) {
            const float f = fac[qq][ss];
            if (f != 0.f)
                sum += (float)accw[((size_t)(b * S + ss) * NLQ + q) * NDV + tid] * f;
        }
    }
    atomicAdd(&out_[b * NDV + tid], sum * (1.f / NLQ));
}

extern "C" void kernel_launch(void* const* d_in, const int* in_sizes, int n_in,
                              void* d_out, int out_size, void* d_ws, size_t ws_size,
                              hipStream_t stream) {
    const float* q    = (const float*)d_in[0];
    const int*   qlen = (const int*)d_in[1];
    const float* k    = (const float*)d_in[2];
    const float* v    = (const float*)d_in[3];
    const int*   mask = (const int*)d_in[4];
    float* out = (float*)d_out;

    int S = SPLITS;   // auto-halve if ws is small (MK sized for S>=MINSPLITS)
    while (S > MINSPLITS &&
           ((size_t)NB * S * NLQ * NDV * 2 + (size_t)NB * S * NLQ * 8) > ws_size)
        S >>= 1;
    f16*   accw = (f16*)d_ws;
    float* mlw  = (float*)((char*)d_ws + (size_t)NB * S * NLQ * NDV * 2);

    hipMemsetAsync(out, 0, (size_t)out_size * sizeof(float), stream);
    dim3 g1(S, NB, 2);   // 2 query-halves of 64
    fvta_part1<<<g1, 256, 0, stream>>>(q, k, v, mask, accw, mlw);
    dim3 g2(NLQ / 8, NB);
    fvta_merge<<<g2, 256, 0, stream>>>(accw, mlw, qlen, out, S);
}